// Round 1
// baseline (309.440 us; speedup 1.0000x reference)
//
#include <hip/hip_runtime.h>
#include <stdint.h>

#define B_N   8192
#define D_K   626
#define KPAD  640
#define KSTEPS 20      // KPAD / 32
#define BM    128
#define BN    128
#define COL_CHUNKS 16
#define TILES_PER_CHUNK 4   // 8192 / (16*128)

typedef __attribute__((ext_vector_type(8))) short short8;   // 8 bf16 in 4 VGPRs
typedef __attribute__((ext_vector_type(4))) float f32x4;

__device__ __forceinline__ unsigned short f32_to_bf16_rne(float x) {
    uint32_t u = __float_as_uint(x);
    uint32_t r = (u + 0x7FFFu + ((u >> 16) & 1u)) >> 16;
    return (unsigned short)r;
}

__device__ __forceinline__ void async16(const unsigned short* g, unsigned short* l) {
    __builtin_amdgcn_global_load_lds(
        (const __attribute__((address_space(1))) unsigned int*)(const void*)g,
        (__attribute__((address_space(3))) unsigned int*)(void*)l,
        16, 0, 0);
}

// ---------------- Kernel 1: row-normalize + convert to bf16 (padded K) ------
__global__ __launch_bounds__(256) void normalize_kernel(
    const float* __restrict__ A, const float* __restrict__ P,
    unsigned short* __restrict__ Abf, unsigned short* __restrict__ Pbf,
    float* __restrict__ rowexp, float* __restrict__ rowsum)
{
    const int r = blockIdx.x;
    const int which = blockIdx.y;
    const float* src = which ? P : A;
    unsigned short* dst = which ? Pbf : Abf;
    const int t = threadIdx.x;

    // k positions covered by this thread: t, t+256, t+512
    float v0 = src[(size_t)r * D_K + t];                       // t < 256 < 626 always valid
    float v1 = src[(size_t)r * D_K + t + 256];                 // t+256 < 512 < 626 always valid
    float v2 = (t + 512 < D_K) ? src[(size_t)r * D_K + t + 512] : 0.0f;

    float ss = v0 * v0 + v1 * v1 + v2 * v2;
    #pragma unroll
    for (int off = 32; off; off >>= 1) ss += __shfl_down(ss, off, 64);

    __shared__ float sred[4];
    if ((t & 63) == 0) sred[t >> 6] = ss;
    __syncthreads();
    const float tot = sred[0] + sred[1] + sred[2] + sred[3];
    const float rn = rsqrtf(tot);   // norms ~25, eps never active

    dst[(size_t)r * KPAD + t]       = f32_to_bf16_rne(v0 * rn);
    dst[(size_t)r * KPAD + t + 256] = f32_to_bf16_rne(v1 * rn);
    const int k2 = t + 512;
    if (k2 < KPAD)
        dst[(size_t)r * KPAD + k2] = (k2 < D_K) ? f32_to_bf16_rne(v2 * rn)
                                                : (unsigned short)0;
    if (which == 0 && t == 0) { rowexp[r] = 0.0f; rowsum[r] = 0.0f; }
}

// ---------------- Kernel 2: fused cosine-GEMM + row reductions --------------
__global__ __launch_bounds__(256) void gemm_fused_kernel(
    const unsigned short* __restrict__ Abf, const unsigned short* __restrict__ Pbf,
    float* __restrict__ rowexp, float* __restrict__ rowsum, float* __restrict__ diag)
{
    __shared__ __align__(16) unsigned short sA[BM * 32];
    __shared__ __align__(16) unsigned short sB[BN * 32];

    const int t    = threadIdx.x;
    const int lane = t & 63;
    const int w    = t >> 6;
    const int wr   = w >> 1;      // wave row (0..1)
    const int wc   = w & 1;       // wave col (0..1)
    const int quad = lane >> 4;
    const int l15  = lane & 15;

    const int rowBase = blockIdx.x * BM;       // 0..63 tiles
    const int chunk   = blockIdx.y;            // 0..15

    // staging: 512 chunks of 8 bf16 (16 B), thread handles c0 = t, c1 = t+256
    const int c0 = t, c1 = t + 256;
    const int sr0 = c0 >> 2, sk0 = (c0 & 3) * 8;
    const int sr1 = c1 >> 2, sk1 = (c1 & 3) * 8;

    const unsigned short* ga0 = Abf + (size_t)(rowBase + sr0) * KPAD + sk0;
    const unsigned short* ga1 = Abf + (size_t)(rowBase + sr1) * KPAD + sk1;
    unsigned short* la0 = &sA[c0 * 8];
    unsigned short* la1 = &sA[c1 * 8];
    unsigned short* lb0 = &sB[c0 * 8];
    unsigned short* lb1 = &sB[c1 * 8];

    // persistent per-lane row partials: [mi][reg]
    float psum[4][4], pexp[4][4];
    #pragma unroll
    for (int i = 0; i < 4; ++i)
        #pragma unroll
        for (int j = 0; j < 4; ++j) { psum[i][j] = 0.0f; pexp[i][j] = 0.0f; }

    for (int ct = 0; ct < TILES_PER_CHUNK; ++ct) {
        const int colBase = (chunk * TILES_PER_CHUNK + ct) * BN;
        const unsigned short* gb0 = Pbf + (size_t)(colBase + sr0) * KPAD + sk0;
        const unsigned short* gb1 = Pbf + (size_t)(colBase + sr1) * KPAD + sk1;

        f32x4 acc[4][4];
        const f32x4 z = {0.f, 0.f, 0.f, 0.f};
        #pragma unroll
        for (int i = 0; i < 4; ++i)
            #pragma unroll
            for (int j = 0; j < 4; ++j) acc[i][j] = z;

        for (int ks = 0; ks < KSTEPS; ++ks) {
            const int kOff = ks * 32;
            __syncthreads();                       // prev compute done with LDS
            async16(ga0 + kOff, la0);
            async16(ga1 + kOff, la1);
            async16(gb0 + kOff, lb0);
            async16(gb1 + kOff, lb1);
            __syncthreads();                       // staging drained (vmcnt 0)

            short8 aF[4], bF[4];
            #pragma unroll
            for (int mi = 0; mi < 4; ++mi)
                aF[mi] = *(const short8*)&sA[(wr * 64 + mi * 16 + l15) * 32 + quad * 8];
            #pragma unroll
            for (int ni = 0; ni < 4; ++ni)
                bF[ni] = *(const short8*)&sB[(wc * 64 + ni * 16 + l15) * 32 + quad * 8];

            #pragma unroll
            for (int mi = 0; mi < 4; ++mi)
                #pragma unroll
                for (int ni = 0; ni < 4; ++ni)
                    acc[mi][ni] = __builtin_amdgcn_mfma_f32_16x16x32_bf16(
                        aF[mi], bF[ni], acc[mi][ni], 0, 0, 0);
        }

        // epilogue: C/D layout col = l15, row = quad*4 + reg
        #pragma unroll
        for (int mi = 0; mi < 4; ++mi) {
            #pragma unroll
            for (int r = 0; r < 4; ++r) {
                const int gr = rowBase + wr * 64 + mi * 16 + quad * 4 + r;
                float s4 = 0.f, e4 = 0.f;
                #pragma unroll
                for (int ni = 0; ni < 4; ++ni) {
                    const float S = acc[mi][ni][r];
                    s4 += S;
                    e4 += __expf(S * 4.0f);        // logits = S / 0.25
                    const int gc = colBase + wc * 64 + ni * 16 + l15;
                    if (gr == gc) diag[gr] = S;
                }
                psum[mi][r] += s4;
                pexp[mi][r] += e4;
            }
        }
    }

    // reduce across the 16 lanes (columns) of each quad-group
    #pragma unroll
    for (int off = 1; off <= 8; off <<= 1) {
        #pragma unroll
        for (int mi = 0; mi < 4; ++mi)
            #pragma unroll
            for (int r = 0; r < 4; ++r) {
                psum[mi][r] += __shfl_xor(psum[mi][r], off, 64);
                pexp[mi][r] += __shfl_xor(pexp[mi][r], off, 64);
            }
    }
    if (l15 == 0) {
        #pragma unroll
        for (int mi = 0; mi < 4; ++mi)
            #pragma unroll
            for (int r = 0; r < 4; ++r) {
                const int gr = rowBase + wr * 64 + mi * 16 + quad * 4 + r;
                atomicAdd(&rowsum[gr], psum[mi][r]);
                atomicAdd(&rowexp[gr], pexp[mi][r]);
            }
    }
}

// ---------------- Kernel 3: final reduction over rows -----------------------
__global__ __launch_bounds__(256) void finalize_kernel(
    const float* __restrict__ rowexp, const float* __restrict__ rowsum,
    const float* __restrict__ diag, float* __restrict__ out)
{
    const int t = threadIdx.x;
    float ls = 0.f, ds = 0.f, ns = 0.f;
    for (int i = t; i < B_N; i += 256) {
        const float d = diag[i];
        ls += __logf(rowexp[i]) - d * 4.0f;   // logsumexp - diag_logit
        ds += d;
        ns += (rowsum[i] - d);
    }
    #pragma unroll
    for (int off = 32; off; off >>= 1) {
        ls += __shfl_down(ls, off, 64);
        ds += __shfl_down(ds, off, 64);
        ns += __shfl_down(ns, off, 64);
    }
    __shared__ float sl[4], sd[4], sn[4];
    if ((t & 63) == 0) { sl[t >> 6] = ls; sd[t >> 6] = ds; sn[t >> 6] = ns; }
    __syncthreads();
    if (t == 0) {
        const float L = sl[0] + sl[1] + sl[2] + sl[3];
        const float Dm = sd[0] + sd[1] + sd[2] + sd[3];
        const float Nn = sn[0] + sn[1] + sn[2] + sn[3];
        out[0] = L / (float)B_N;
        out[1] = Dm / (float)B_N;
        out[2] = (Nn / (float)(B_N - 1)) / (float)B_N;
    }
}

// ---------------- Fallback path (small workspace): fp32 vector --------------
__global__ __launch_bounds__(256) void fb_norm(
    const float* __restrict__ A, const float* __restrict__ P,
    float* __restrict__ rna, float* __restrict__ rnp, float* __restrict__ acc)
{
    const int r = blockIdx.x;
    const float* src = blockIdx.y ? P : A;
    const int t = threadIdx.x;
    float ss = 0.f;
    for (int k = t; k < D_K; k += 256) { float v = src[(size_t)r * D_K + k]; ss += v * v; }
    #pragma unroll
    for (int off = 32; off; off >>= 1) ss += __shfl_down(ss, off, 64);
    __shared__ float sred[4];
    if ((t & 63) == 0) sred[t >> 6] = ss;
    __syncthreads();
    if (t == 0) {
        const float rn = rsqrtf(sred[0] + sred[1] + sred[2] + sred[3]);
        (blockIdx.y ? rnp : rna)[r] = rn;
    }
    if (blockIdx.x == 0 && blockIdx.y == 0 && t < 3) acc[t] = 0.0f;
}

__global__ __launch_bounds__(256) void fb_main(
    const float* __restrict__ A, const float* __restrict__ P,
    const float* __restrict__ rna, const float* __restrict__ rnp,
    float* __restrict__ acc)
{
    __shared__ float sa[D_K];
    __shared__ float red[12];
    const int i = blockIdx.x;
    const int t = threadIdx.x;
    const float rn = rna[i];
    for (int k = t; k < D_K; k += 256) sa[k] = A[(size_t)i * D_K + k] * rn;
    __syncthreads();
    const int w = t >> 6, lane = t & 63;
    float we = 0.f, wsum = 0.f, wd = 0.f;
    for (int j = w; j < B_N; j += 4) {
        float dot = 0.f;
        const float* p = P + (size_t)j * D_K;
        for (int k = lane; k < D_K; k += 64) dot += sa[k] * p[k];
        #pragma unroll
        for (int off = 32; off; off >>= 1) dot += __shfl_xor(dot, off, 64);
        const float S = dot * rnp[j];
        we += __expf(S * 4.0f);
        wsum += S;
        if (j == i) wd = S;
    }
    if (lane == 0) { red[w] = we; red[4 + w] = wsum; red[8 + w] = wd; }
    __syncthreads();
    if (t == 0) {
        const float E  = red[0] + red[1] + red[2] + red[3];
        const float Sm = red[4] + red[5] + red[6] + red[7];
        const float Dd = red[8] + red[9] + red[10] + red[11];
        atomicAdd(acc + 0, __logf(E) - 4.0f * Dd);
        atomicAdd(acc + 1, Dd);
        atomicAdd(acc + 2, Sm - Dd);
    }
}

__global__ void fb_fin(const float* __restrict__ acc, float* __restrict__ out)
{
    out[0] = acc[0] / (float)B_N;
    out[1] = acc[1] / (float)B_N;
    out[2] = acc[2] / ((float)(B_N - 1) * (float)B_N);
}

// ---------------------------------------------------------------------------
extern "C" void kernel_launch(void* const* d_in, const int* in_sizes, int n_in,
                              void* d_out, int out_size, void* d_ws, size_t ws_size,
                              hipStream_t stream)
{
    const float* A = (const float*)d_in[0];
    const float* P = (const float*)d_in[1];
    float* out = (float*)d_out;
    char* ws = (char*)d_ws;

    const size_t ABF_OFF  = 0;
    const size_t PBF_OFF  = ABF_OFF + (size_t)B_N * KPAD * sizeof(unsigned short);
    const size_t REXP_OFF = PBF_OFF + (size_t)B_N * KPAD * sizeof(unsigned short);
    const size_t RSUM_OFF = REXP_OFF + (size_t)B_N * sizeof(float);
    const size_t DIAG_OFF = RSUM_OFF + (size_t)B_N * sizeof(float);
    const size_t MAIN_REQ = DIAG_OFF + (size_t)B_N * sizeof(float);

    if (ws_size >= MAIN_REQ) {
        unsigned short* Abf = (unsigned short*)(ws + ABF_OFF);
        unsigned short* Pbf = (unsigned short*)(ws + PBF_OFF);
        float* rowexp = (float*)(ws + REXP_OFF);
        float* rowsum = (float*)(ws + RSUM_OFF);
        float* diag   = (float*)(ws + DIAG_OFF);

        normalize_kernel<<<dim3(B_N, 2), 256, 0, stream>>>(A, P, Abf, Pbf, rowexp, rowsum);
        gemm_fused_kernel<<<dim3(B_N / BM, COL_CHUNKS), 256, 0, stream>>>(
            Abf, Pbf, rowexp, rowsum, diag);
        finalize_kernel<<<1, 256, 0, stream>>>(rowexp, rowsum, diag, out);
    } else {
        // slow-but-correct fp32 fallback (needs ~96 KB ws)
        float* rna = (float*)ws;
        float* rnp = rna + B_N;
        float* acc = rnp + B_N;
        fb_norm<<<dim3(B_N, 2), 256, 0, stream>>>(A, P, rna, rnp, acc);
        fb_main<<<B_N, 256, 0, stream>>>(A, P, rna, rnp, acc);
        fb_fin<<<1, 1, 0, stream>>>(acc, out);
    }
}

// Round 2
// 280.174 us; speedup vs baseline: 1.1045x; 1.1045x over previous
//
#include <hip/hip_runtime.h>
#include <stdint.h>

#define B_N   8192
#define D_K   626
#define KPAD  640
#define BK    64
#define KSTEPS 10      // KPAD / BK
#define BM    128
#define BN    128
#define COL_CHUNKS 16
#define TILES_PER_CHUNK 4   // 8192 / (16*128)

typedef __attribute__((ext_vector_type(8))) short short8;   // 8 bf16 in 4 VGPRs
typedef __attribute__((ext_vector_type(4))) float f32x4;

__device__ __forceinline__ unsigned short f32_to_bf16_rne(float x) {
    uint32_t u = __float_as_uint(x);
    uint32_t r = (u + 0x7FFFu + ((u >> 16) & 1u)) >> 16;
    return (unsigned short)r;
}

__device__ __forceinline__ void async16(const unsigned short* g, unsigned short* l) {
    __builtin_amdgcn_global_load_lds(
        (const __attribute__((address_space(1))) unsigned int*)(const void*)g,
        (__attribute__((address_space(3))) unsigned int*)(void*)l,
        16, 0, 0);
}

// ---------------- Kernel 1: row-normalize + convert to bf16 (padded K) ------
// 192 threads/row: t<156 -> 4 floats via two float2 (row base only 8B-aligned),
// t==156 -> tail floats 624,625; t in [156,160) also zero-pad KPAD region.
__global__ __launch_bounds__(192) void normalize_kernel(
    const float* __restrict__ A, const float* __restrict__ P,
    unsigned short* __restrict__ Abf, unsigned short* __restrict__ Pbf,
    float* __restrict__ rowexp, float* __restrict__ rowsum)
{
    const int r = blockIdx.x;
    const int which = blockIdx.y;
    const float* src = (which ? P : A) + (size_t)r * D_K;
    unsigned short* dst = (which ? Pbf : Abf) + (size_t)r * KPAD;
    const int t = threadIdx.x;

    float x0 = 0.f, x1 = 0.f, x2 = 0.f, x3 = 0.f;
    if (t < 156) {
        float2 a = ((const float2*)src)[2 * t];
        float2 b = ((const float2*)src)[2 * t + 1];
        x0 = a.x; x1 = a.y; x2 = b.x; x3 = b.y;
    } else if (t == 156) {
        float2 a = ((const float2*)src)[312];   // elements 624, 625
        x0 = a.x; x1 = a.y;
    }

    float ss = x0 * x0 + x1 * x1 + x2 * x2 + x3 * x3;
    #pragma unroll
    for (int off = 32; off; off >>= 1) ss += __shfl_down(ss, off, 64);

    __shared__ float sred[3];
    if ((t & 63) == 0) sred[t >> 6] = ss;
    __syncthreads();
    const float rn = rsqrtf(sred[0] + sred[1] + sred[2]);  // norms ~25, eps never active

    if (t < 160) {
        ushort4 o;
        o.x = f32_to_bf16_rne(x0 * rn);
        o.y = f32_to_bf16_rne(x1 * rn);
        o.z = f32_to_bf16_rne(x2 * rn);
        o.w = f32_to_bf16_rne(x3 * rn);
        ((ushort4*)dst)[t] = o;   // covers elements [4t, 4t+4); t>=157 writes zeros (pad)
    }
    if (which == 0 && t == 0) { rowexp[r] = 0.0f; rowsum[r] = 0.0f; }
}

// ---------------- Kernel 2: fused cosine-GEMM + row reductions --------------
// LDS layout (per matrix): 16B chunk position p = row*8 + kq'  (kq' = kq ^ (row&7))
// The XOR swizzle is applied on the GLOBAL source address during staging, so the
// global_load_lds lane-ordered LDS destination constraint still holds, while the
// fragment ds_read_b128 hits all 8 banksets evenly (2 lanes/bankset == free).
__global__ __launch_bounds__(256, 3) void gemm_fused_kernel(
    const unsigned short* __restrict__ Abf, const unsigned short* __restrict__ Pbf,
    float* __restrict__ rowexp, float* __restrict__ rowsum, float* __restrict__ diag)
{
    __shared__ __align__(16) unsigned short sA[BM * BK];
    __shared__ __align__(16) unsigned short sB[BN * BK];

    const int t    = threadIdx.x;
    const int lane = t & 63;
    const int w    = t >> 6;
    const int wr   = w >> 1;      // wave row (0..1)
    const int wc   = w & 1;       // wave col (0..1)
    const int quad = lane >> 4;
    const int l15  = lane & 15;
    const int rx   = l15 & 7;

    const int rowBase = blockIdx.x * BM;       // 64 row-tiles
    const int chunk   = blockIdx.y;            // 16 col-chunks

    // staging: 1024 chunks per matrix, 4 per thread (p = t + j*256)
    const int p0 = t, p1 = t + 256, p2 = t + 512, p3 = t + 768;
    const int r0 = p0 >> 3, r1 = p1 >> 3, r2 = p2 >> 3, r3 = p3 >> 3;
    const size_t g0 = (size_t)r0 * KPAD + (size_t)(((p0 & 7) ^ (r0 & 7)) * 8);
    const size_t g1 = (size_t)r1 * KPAD + (size_t)(((p1 & 7) ^ (r1 & 7)) * 8);
    const size_t g2 = (size_t)r2 * KPAD + (size_t)(((p2 & 7) ^ (r2 & 7)) * 8);
    const size_t g3 = (size_t)r3 * KPAD + (size_t)(((p3 & 7) ^ (r3 & 7)) * 8);

    const unsigned short* Ab = Abf + (size_t)rowBase * KPAD;
    const unsigned short* gA0 = Ab + g0;
    const unsigned short* gA1 = Ab + g1;
    const unsigned short* gA2 = Ab + g2;
    const unsigned short* gA3 = Ab + g3;
    unsigned short* lA0 = &sA[p0 * 8];
    unsigned short* lA1 = &sA[p1 * 8];
    unsigned short* lA2 = &sA[p2 * 8];
    unsigned short* lA3 = &sA[p3 * 8];
    unsigned short* lB0 = &sB[p0 * 8];
    unsigned short* lB1 = &sB[p1 * 8];
    unsigned short* lB2 = &sB[p2 * 8];
    unsigned short* lB3 = &sB[p3 * 8];

    // fragment read offsets (shorts): idx = (row + mi*16)*BK + ((h*4+quad)^rx)*8
    const int aRow = wr * 64 + l15;
    const int bRow = wc * 64 + l15;
    const int kq0 = ((quad) ^ rx) * 8;
    const int kq1 = ((4 + quad) ^ rx) * 8;

    // persistent per-lane row partials: [mi][reg]
    float psum[4][4], pexp[4][4];
    #pragma unroll
    for (int i = 0; i < 4; ++i)
        #pragma unroll
        for (int j = 0; j < 4; ++j) { psum[i][j] = 0.0f; pexp[i][j] = 0.0f; }

    for (int ct = 0; ct < TILES_PER_CHUNK; ++ct) {
        const int colBase = (chunk * TILES_PER_CHUNK + ct) * BN;
        const unsigned short* Pb = Pbf + (size_t)colBase * KPAD;
        const unsigned short* gB0 = Pb + g0;
        const unsigned short* gB1 = Pb + g1;
        const unsigned short* gB2 = Pb + g2;
        const unsigned short* gB3 = Pb + g3;

        f32x4 acc[4][4];
        const f32x4 z = {0.f, 0.f, 0.f, 0.f};
        #pragma unroll
        for (int i = 0; i < 4; ++i)
            #pragma unroll
            for (int j = 0; j < 4; ++j) acc[i][j] = z;

        for (int ks = 0; ks < KSTEPS; ++ks) {
            const int kOff = ks * BK;
            __syncthreads();                       // prev compute done with LDS
            async16(gA0 + kOff, lA0);
            async16(gA1 + kOff, lA1);
            async16(gA2 + kOff, lA2);
            async16(gA3 + kOff, lA3);
            async16(gB0 + kOff, lB0);
            async16(gB1 + kOff, lB1);
            async16(gB2 + kOff, lB2);
            async16(gB3 + kOff, lB3);
            __syncthreads();                       // staging drained

            #pragma unroll
            for (int h = 0; h < 2; ++h) {
                const int kqh = h ? kq1 : kq0;
                short8 aF[4], bF[4];
                #pragma unroll
                for (int mi = 0; mi < 4; ++mi)
                    aF[mi] = *(const short8*)&sA[(aRow + mi * 16) * BK + kqh];
                #pragma unroll
                for (int ni = 0; ni < 4; ++ni)
                    bF[ni] = *(const short8*)&sB[(bRow + ni * 16) * BK + kqh];

                #pragma unroll
                for (int mi = 0; mi < 4; ++mi)
                    #pragma unroll
                    for (int ni = 0; ni < 4; ++ni)
                        acc[mi][ni] = __builtin_amdgcn_mfma_f32_16x16x32_bf16(
                            aF[mi], bF[ni], acc[mi][ni], 0, 0, 0);
            }
        }

        // diagonal tile: rare, uniform branch
        if (rowBase == colBase && wr == wc) {
            #pragma unroll
            for (int mi = 0; mi < 4; ++mi)
                #pragma unroll
                for (int r = 0; r < 4; ++r)
                    if (l15 == quad * 4 + r)
                        diag[rowBase + wr * 64 + mi * 16 + l15] = acc[mi][mi][r];
        }

        // epilogue: C/D layout col = l15, row = quad*4 + reg
        #pragma unroll
        for (int mi = 0; mi < 4; ++mi) {
            #pragma unroll
            for (int r = 0; r < 4; ++r) {
                float s4 = 0.f, e4 = 0.f;
                #pragma unroll
                for (int ni = 0; ni < 4; ++ni) {
                    const float S = acc[mi][ni][r];
                    s4 += S;
                    e4 += __expf(S * 4.0f);        // logits = S / 0.25
                }
                psum[mi][r] += s4;
                pexp[mi][r] += e4;
            }
        }
    }

    // reduce across the 16 columns (l15 lanes) of each quad-group
    #pragma unroll
    for (int off = 1; off <= 8; off <<= 1) {
        #pragma unroll
        for (int mi = 0; mi < 4; ++mi)
            #pragma unroll
            for (int r = 0; r < 4; ++r) {
                psum[mi][r] += __shfl_xor(psum[mi][r], off, 64);
                pexp[mi][r] += __shfl_xor(pexp[mi][r], off, 64);
            }
    }
    if (l15 == 0) {
        #pragma unroll
        for (int mi = 0; mi < 4; ++mi)
            #pragma unroll
            for (int r = 0; r < 4; ++r) {
                const int gr = rowBase + wr * 64 + mi * 16 + quad * 4 + r;
                atomicAdd(&rowsum[gr], psum[mi][r]);
                atomicAdd(&rowexp[gr], pexp[mi][r]);
            }
    }
}

// ---------------- Kernel 3: final reduction over rows -----------------------
__global__ __launch_bounds__(256) void finalize_kernel(
    const float* __restrict__ rowexp, const float* __restrict__ rowsum,
    const float* __restrict__ diag, float* __restrict__ out)
{
    const int t = threadIdx.x;
    float ls = 0.f, ds = 0.f, ns = 0.f;
    for (int i = t; i < B_N; i += 256) {
        const float d = diag[i];
        ls += __logf(rowexp[i]) - d * 4.0f;   // logsumexp - diag_logit
        ds += d;
        ns += (rowsum[i] - d);
    }
    #pragma unroll
    for (int off = 32; off; off >>= 1) {
        ls += __shfl_down(ls, off, 64);
        ds += __shfl_down(ds, off, 64);
        ns += __shfl_down(ns, off, 64);
    }
    __shared__ float sl[4], sd[4], sn[4];
    if ((t & 63) == 0) { sl[t >> 6] = ls; sd[t >> 6] = ds; sn[t >> 6] = ns; }
    __syncthreads();
    if (t == 0) {
        const float L = sl[0] + sl[1] + sl[2] + sl[3];
        const float Dm = sd[0] + sd[1] + sd[2] + sd[3];
        const float Nn = sn[0] + sn[1] + sn[2] + sn[3];
        out[0] = L / (float)B_N;
        out[1] = Dm / (float)B_N;
        out[2] = (Nn / (float)(B_N - 1)) / (float)B_N;
    }
}

// ---------------- Fallback path (small workspace): fp32 vector --------------
__global__ __launch_bounds__(256) void fb_norm(
    const float* __restrict__ A, const float* __restrict__ P,
    float* __restrict__ rna, float* __restrict__ rnp, float* __restrict__ acc)
{
    const int r = blockIdx.x;
    const float* src = blockIdx.y ? P : A;
    const int t = threadIdx.x;
    float ss = 0.f;
    for (int k = t; k < D_K; k += 256) { float v = src[(size_t)r * D_K + k]; ss += v * v; }
    #pragma unroll
    for (int off = 32; off; off >>= 1) ss += __shfl_down(ss, off, 64);
    __shared__ float sred[4];
    if ((t & 63) == 0) sred[t >> 6] = ss;
    __syncthreads();
    if (t == 0) {
        const float rn = rsqrtf(sred[0] + sred[1] + sred[2] + sred[3]);
        (blockIdx.y ? rnp : rna)[r] = rn;
    }
    if (blockIdx.x == 0 && blockIdx.y == 0 && t < 3) acc[t] = 0.0f;
}

__global__ __launch_bounds__(256) void fb_main(
    const float* __restrict__ A, const float* __restrict__ P,
    const float* __restrict__ rna, const float* __restrict__ rnp,
    float* __restrict__ acc)
{
    __shared__ float sa[D_K];
    __shared__ float red[12];
    const int i = blockIdx.x;
    const int t = threadIdx.x;
    const float rn = rna[i];
    for (int k = t; k < D_K; k += 256) sa[k] = A[(size_t)i * D_K + k] * rn;
    __syncthreads();
    const int w = t >> 6, lane = t & 63;
    float we = 0.f, wsum = 0.f, wd = 0.f;
    for (int j = w; j < B_N; j += 4) {
        float dot = 0.f;
        const float* p = P + (size_t)j * D_K;
        for (int k = lane; k < D_K; k += 64) dot += sa[k] * p[k];
        #pragma unroll
        for (int off = 32; off; off >>= 1) dot += __shfl_xor(dot, off, 64);
        const float S = dot * rnp[j];
        we += __expf(S * 4.0f);
        wsum += S;
        if (j == i) wd = S;
    }
    if (lane == 0) { red[w] = we; red[4 + w] = wsum; red[8 + w] = wd; }
    __syncthreads();
    if (t == 0) {
        const float E  = red[0] + red[1] + red[2] + red[3];
        const float Sm = red[4] + red[5] + red[6] + red[7];
        const float Dd = red[8] + red[9] + red[10] + red[11];
        atomicAdd(acc + 0, __logf(E) - 4.0f * Dd);
        atomicAdd(acc + 1, Dd);
        atomicAdd(acc + 2, Sm - Dd);
    }
}

__global__ void fb_fin(const float* __restrict__ acc, float* __restrict__ out)
{
    out[0] = acc[0] / (float)B_N;
    out[1] = acc[1] / (float)B_N;
    out[2] = acc[2] / ((float)(B_N - 1) * (float)B_N);
}

// ---------------------------------------------------------------------------
extern "C" void kernel_launch(void* const* d_in, const int* in_sizes, int n_in,
                              void* d_out, int out_size, void* d_ws, size_t ws_size,
                              hipStream_t stream)
{
    const float* A = (const float*)d_in[0];
    const float* P = (const float*)d_in[1];
    float* out = (float*)d_out;
    char* ws = (char*)d_ws;

    const size_t ABF_OFF  = 0;
    const size_t PBF_OFF  = ABF_OFF + (size_t)B_N * KPAD * sizeof(unsigned short);
    const size_t REXP_OFF = PBF_OFF + (size_t)B_N * KPAD * sizeof(unsigned short);
    const size_t RSUM_OFF = REXP_OFF + (size_t)B_N * sizeof(float);
    const size_t DIAG_OFF = RSUM_OFF + (size_t)B_N * sizeof(float);
    const size_t MAIN_REQ = DIAG_OFF + (size_t)B_N * sizeof(float);

    if (ws_size >= MAIN_REQ) {
        unsigned short* Abf = (unsigned short*)(ws + ABF_OFF);
        unsigned short* Pbf = (unsigned short*)(ws + PBF_OFF);
        float* rowexp = (float*)(ws + REXP_OFF);
        float* rowsum = (float*)(ws + RSUM_OFF);
        float* diag   = (float*)(ws + DIAG_OFF);

        normalize_kernel<<<dim3(B_N, 2), 192, 0, stream>>>(A, P, Abf, Pbf, rowexp, rowsum);
        gemm_fused_kernel<<<dim3(B_N / BM, COL_CHUNKS), 256, 0, stream>>>(
            Abf, Pbf, rowexp, rowsum, diag);
        finalize_kernel<<<1, 256, 0, stream>>>(rowexp, rowsum, diag, out);
    } else {
        // slow-but-correct fp32 fallback (needs ~96 KB ws)
        float* rna = (float*)ws;
        float* rnp = rna + B_N;
        float* acc = rnp + B_N;
        fb_norm<<<dim3(B_N, 2), 256, 0, stream>>>(A, P, rna, rnp, acc);
        fb_main<<<B_N, 256, 0, stream>>>(A, P, rna, rnp, acc);
        fb_fin<<<1, 1, 0, stream>>>(acc, out);
    }
}

// Round 3
// 189.047 us; speedup vs baseline: 1.6368x; 1.4820x over previous
//
#include <hip/hip_runtime.h>
#include <stdint.h>

#define B_N   8192
#define D_K   626
#define KPAD  640        // fp8 bytes per row (padded)
#define BK    128        // K-bytes per step
#define KSTEPS 5         // KPAD / BK
#define BM    128
#define BN    128
#define COL_CHUNKS 16
#define TILES_PER_CHUNK 4   // 8192 / (16*128)
#define FIN_BLOCKS 16

typedef __attribute__((ext_vector_type(4))) float f32x4;

__device__ __forceinline__ void async16(const unsigned char* g, unsigned char* l) {
    __builtin_amdgcn_global_load_lds(
        (const __attribute__((address_space(1))) unsigned int*)(const void*)g,
        (__attribute__((address_space(3))) unsigned int*)(void*)l,
        16, 0, 0);
}

// ---------------- Kernel 1: row-normalize + convert to fp8 e4m3 (padded K) --
// 192 threads/row: t<156 -> 4 floats via two float2; t==156 -> tail (624,625);
// t in [157,160) write zero padding. Output row = 640 fp8 bytes (160 uints).
__global__ __launch_bounds__(192) void normalize_kernel(
    const float* __restrict__ A, const float* __restrict__ P,
    unsigned char* __restrict__ Af8, unsigned char* __restrict__ Pf8,
    float* __restrict__ rowexp, float* __restrict__ rowsum, float* __restrict__ acc)
{
    const int r = blockIdx.x;
    const int which = blockIdx.y;
    const float* src = (which ? P : A) + (size_t)r * D_K;
    unsigned char* dst = (which ? Pf8 : Af8) + (size_t)r * KPAD;
    const int t = threadIdx.x;

    float x0 = 0.f, x1 = 0.f, x2 = 0.f, x3 = 0.f;
    if (t < 156) {
        float2 a = ((const float2*)src)[2 * t];
        float2 b = ((const float2*)src)[2 * t + 1];
        x0 = a.x; x1 = a.y; x2 = b.x; x3 = b.y;
    } else if (t == 156) {
        float2 a = ((const float2*)src)[312];   // elements 624, 625
        x0 = a.x; x1 = a.y;
    }

    float ss = x0 * x0 + x1 * x1 + x2 * x2 + x3 * x3;
    #pragma unroll
    for (int off = 32; off; off >>= 1) ss += __shfl_down(ss, off, 64);

    __shared__ float sred[3];
    if ((t & 63) == 0) sred[t >> 6] = ss;
    __syncthreads();
    const float rn = rsqrtf(sred[0] + sred[1] + sred[2]);  // norms ~25, eps never active

    if (t < 160) {
        int pk = __builtin_amdgcn_cvt_pk_fp8_f32(x0 * rn, x1 * rn, 0, false);
        pk = __builtin_amdgcn_cvt_pk_fp8_f32(x2 * rn, x3 * rn, pk, true);
        ((int*)dst)[t] = pk;   // covers bytes [4t,4t+4); t>=157 writes zeros (pad)
    }
    if (which == 0 && t == 0) { rowexp[r] = 0.0f; rowsum[r] = 0.0f; }
    if (which == 0 && r == 0 && t < 3) acc[t] = 0.0f;
}

// ---------------- Kernel 2: fused fp8 cosine-GEMM + row reductions ----------
// LDS row = 128 B = 8 chunks of 16 B; staging applies XOR swizzle on the GLOBAL
// source (c16' = c16 ^ (row&7)) so global_load_lds keeps its lane-ordered dest
// while fragment ds_read_b64 spreads across all 32 banks (2-way aliasing = free).
__global__ __launch_bounds__(256, 3) void gemm_fused_kernel(
    const unsigned char* __restrict__ Af8, const unsigned char* __restrict__ Pf8,
    float* __restrict__ rowexp, float* __restrict__ rowsum, float* __restrict__ diag)
{
    __shared__ __align__(16) unsigned char sA[BM * BK];   // 16 KB
    __shared__ __align__(16) unsigned char sB[BN * BK];   // 16 KB

    const int t    = threadIdx.x;
    const int lane = t & 63;
    const int w    = t >> 6;
    const int wr   = w >> 1;      // wave row (0..1)
    const int wc   = w & 1;       // wave col (0..1)
    const int quad = lane >> 4;
    const int l15  = lane & 15;
    const int rx   = l15 & 7;
    const int qh   = quad >> 1;        // which 16B half-pair
    const int qb   = (quad & 1) * 8;   // byte offset inside 16B chunk

    const int rowBase = blockIdx.x * BM;       // 64 row-tiles
    const int chunk   = blockIdx.y;            // 16 col-chunks

    // staging: per matrix 1024 chunks of 16 B, 4 per thread (p = t + j*256)
    const int p0 = t, p1 = t + 256, p2 = t + 512, p3 = t + 768;
    const int r0 = p0 >> 3, r1 = p1 >> 3, r2 = p2 >> 3, r3 = p3 >> 3;
    const size_t g0 = (size_t)r0 * KPAD + (size_t)(((p0 & 7) ^ (r0 & 7)) * 16);
    const size_t g1 = (size_t)r1 * KPAD + (size_t)(((p1 & 7) ^ (r1 & 7)) * 16);
    const size_t g2 = (size_t)r2 * KPAD + (size_t)(((p2 & 7) ^ (r2 & 7)) * 16);
    const size_t g3 = (size_t)r3 * KPAD + (size_t)(((p3 & 7) ^ (r3 & 7)) * 16);

    const unsigned char* Ab = Af8 + (size_t)rowBase * KPAD;
    const unsigned char* gA0 = Ab + g0;
    const unsigned char* gA1 = Ab + g1;
    const unsigned char* gA2 = Ab + g2;
    const unsigned char* gA3 = Ab + g3;
    unsigned char* lA0 = &sA[p0 * 16];
    unsigned char* lA1 = &sA[p1 * 16];
    unsigned char* lA2 = &sA[p2 * 16];
    unsigned char* lA3 = &sA[p3 * 16];
    unsigned char* lB0 = &sB[p0 * 16];
    unsigned char* lB1 = &sB[p1 * 16];
    unsigned char* lB2 = &sB[p2 * 16];
    unsigned char* lB3 = &sB[p3 * 16];

    // fragment read offsets: addr = (row + mi*16)*BK + ((h*2+qh)^rx)*16 + qb
    const int aRow = wr * 64 + l15;
    const int bRow = wc * 64 + l15;
    int cOff[4];
    #pragma unroll
    for (int h = 0; h < 4; ++h) cOff[h] = ((h * 2 + qh) ^ rx) * 16 + qb;

    // persistent per-lane row partials: [mi][reg]
    float psum[4][4], pexp[4][4];
    #pragma unroll
    for (int i = 0; i < 4; ++i)
        #pragma unroll
        for (int j = 0; j < 4; ++j) { psum[i][j] = 0.0f; pexp[i][j] = 0.0f; }

    for (int ct = 0; ct < TILES_PER_CHUNK; ++ct) {
        const int colBase = (chunk * TILES_PER_CHUNK + ct) * BN;
        const unsigned char* Pb = Pf8 + (size_t)colBase * KPAD;
        const unsigned char* gB0 = Pb + g0;
        const unsigned char* gB1 = Pb + g1;
        const unsigned char* gB2 = Pb + g2;
        const unsigned char* gB3 = Pb + g3;

        f32x4 acc[4][4];
        const f32x4 z = {0.f, 0.f, 0.f, 0.f};
        #pragma unroll
        for (int i = 0; i < 4; ++i)
            #pragma unroll
            for (int j = 0; j < 4; ++j) acc[i][j] = z;

        for (int ks = 0; ks < KSTEPS; ++ks) {
            const int kOff = ks * BK;
            __syncthreads();                       // prev compute done with LDS
            async16(gA0 + kOff, lA0);
            async16(gA1 + kOff, lA1);
            async16(gA2 + kOff, lA2);
            async16(gA3 + kOff, lA3);
            async16(gB0 + kOff, lB0);
            async16(gB1 + kOff, lB1);
            async16(gB2 + kOff, lB2);
            async16(gB3 + kOff, lB3);
            __syncthreads();                       // staging drained

            #pragma unroll
            for (int h = 0; h < 4; ++h) {          // 4 K-halves of 32 bytes
                long aF[4], bF[4];
                #pragma unroll
                for (int mi = 0; mi < 4; ++mi)
                    aF[mi] = *(const long*)&sA[(aRow + mi * 16) * BK + cOff[h]];
                #pragma unroll
                for (int ni = 0; ni < 4; ++ni)
                    bF[ni] = *(const long*)&sB[(bRow + ni * 16) * BK + cOff[h]];

                #pragma unroll
                for (int mi = 0; mi < 4; ++mi)
                    #pragma unroll
                    for (int ni = 0; ni < 4; ++ni)
                        acc[mi][ni] = __builtin_amdgcn_mfma_f32_16x16x32_fp8_fp8(
                            aF[mi], bF[ni], acc[mi][ni], 0, 0, 0);
            }
        }

        // diagonal tile: rare, uniform branch
        if (rowBase == colBase && wr == wc) {
            #pragma unroll
            for (int mi = 0; mi < 4; ++mi)
                #pragma unroll
                for (int r = 0; r < 4; ++r)
                    if (l15 == quad * 4 + r)
                        diag[rowBase + wr * 64 + mi * 16 + l15] = acc[mi][mi][r];
        }

        // epilogue: C/D layout col = l15, row = quad*4 + reg
        #pragma unroll
        for (int mi = 0; mi < 4; ++mi) {
            #pragma unroll
            for (int r = 0; r < 4; ++r) {
                float s4 = 0.f, e4 = 0.f;
                #pragma unroll
                for (int ni = 0; ni < 4; ++ni) {
                    const float S = acc[mi][ni][r];
                    s4 += S;
                    e4 += __expf(S * 4.0f);        // logits = S / 0.25
                }
                psum[mi][r] += s4;
                pexp[mi][r] += e4;
            }
        }
    }

    // reduce across the 16 columns (l15 lanes) of each quad-group
    #pragma unroll
    for (int off = 1; off <= 8; off <<= 1) {
        #pragma unroll
        for (int mi = 0; mi < 4; ++mi)
            #pragma unroll
            for (int r = 0; r < 4; ++r) {
                psum[mi][r] += __shfl_xor(psum[mi][r], off, 64);
                pexp[mi][r] += __shfl_xor(pexp[mi][r], off, 64);
            }
    }
    if (l15 == 0) {
        #pragma unroll
        for (int mi = 0; mi < 4; ++mi)
            #pragma unroll
            for (int r = 0; r < 4; ++r) {
                const int gr = rowBase + wr * 64 + mi * 16 + quad * 4 + r;
                atomicAdd(&rowsum[gr], psum[mi][r]);
                atomicAdd(&rowexp[gr], pexp[mi][r]);
            }
    }
}

// ---------------- Kernel 3a: parallel final reduction over rows -------------
__global__ __launch_bounds__(256) void finalize_partial(
    const float* __restrict__ rowexp, const float* __restrict__ rowsum,
    const float* __restrict__ diag, float* __restrict__ acc)
{
    const int t = threadIdx.x;
    float ls = 0.f, ds = 0.f, ns = 0.f;
    for (int i = blockIdx.x * 256 + t; i < B_N; i += FIN_BLOCKS * 256) {
        const float d = diag[i];
        ls += __logf(rowexp[i]) - d * 4.0f;   // logsumexp - diag_logit
        ds += d;
        ns += (rowsum[i] - d);
    }
    #pragma unroll
    for (int off = 32; off; off >>= 1) {
        ls += __shfl_down(ls, off, 64);
        ds += __shfl_down(ds, off, 64);
        ns += __shfl_down(ns, off, 64);
    }
    __shared__ float sl[4], sd[4], sn[4];
    if ((t & 63) == 0) { sl[t >> 6] = ls; sd[t >> 6] = ds; sn[t >> 6] = ns; }
    __syncthreads();
    if (t == 0) {
        atomicAdd(acc + 0, sl[0] + sl[1] + sl[2] + sl[3]);
        atomicAdd(acc + 1, sd[0] + sd[1] + sd[2] + sd[3]);
        atomicAdd(acc + 2, sn[0] + sn[1] + sn[2] + sn[3]);
    }
}

__global__ void finalize_write(const float* __restrict__ acc, float* __restrict__ out)
{
    out[0] = acc[0] / (float)B_N;
    out[1] = acc[1] / (float)B_N;
    out[2] = acc[2] / ((float)(B_N - 1) * (float)B_N);
}

// ---------------- Fallback path (small workspace): fp32 vector --------------
__global__ __launch_bounds__(256) void fb_norm(
    const float* __restrict__ A, const float* __restrict__ P,
    float* __restrict__ rna, float* __restrict__ rnp, float* __restrict__ acc)
{
    const int r = blockIdx.x;
    const float* src = blockIdx.y ? P : A;
    const int t = threadIdx.x;
    float ss = 0.f;
    for (int k = t; k < D_K; k += 256) { float v = src[(size_t)r * D_K + k]; ss += v * v; }
    #pragma unroll
    for (int off = 32; off; off >>= 1) ss += __shfl_down(ss, off, 64);
    __shared__ float sred[4];
    if ((t & 63) == 0) sred[t >> 6] = ss;
    __syncthreads();
    if (t == 0) {
        const float rn = rsqrtf(sred[0] + sred[1] + sred[2] + sred[3]);
        (blockIdx.y ? rnp : rna)[r] = rn;
    }
    if (blockIdx.x == 0 && blockIdx.y == 0 && t < 3) acc[t] = 0.0f;
}

__global__ __launch_bounds__(256) void fb_main(
    const float* __restrict__ A, const float* __restrict__ P,
    const float* __restrict__ rna, const float* __restrict__ rnp,
    float* __restrict__ acc)
{
    __shared__ float sa[D_K];
    __shared__ float red[12];
    const int i = blockIdx.x;
    const int t = threadIdx.x;
    const float rn = rna[i];
    for (int k = t; k < D_K; k += 256) sa[k] = A[(size_t)i * D_K + k] * rn;
    __syncthreads();
    const int w = t >> 6, lane = t & 63;
    float we = 0.f, wsum = 0.f, wd = 0.f;
    for (int j = w; j < B_N; j += 4) {
        float dot = 0.f;
        const float* p = P + (size_t)j * D_K;
        for (int k = lane; k < D_K; k += 64) dot += sa[k] * p[k];
        #pragma unroll
        for (int off = 32; off; off >>= 1) dot += __shfl_xor(dot, off, 64);
        const float S = dot * rnp[j];
        we += __expf(S * 4.0f);
        wsum += S;
        if (j == i) wd = S;
    }
    if (lane == 0) { red[w] = we; red[4 + w] = wsum; red[8 + w] = wd; }
    __syncthreads();
    if (t == 0) {
        const float E  = red[0] + red[1] + red[2] + red[3];
        const float Sm = red[4] + red[5] + red[6] + red[7];
        const float Dd = red[8] + red[9] + red[10] + red[11];
        atomicAdd(acc + 0, __logf(E) - 4.0f * Dd);
        atomicAdd(acc + 1, Dd);
        atomicAdd(acc + 2, Sm - Dd);
    }
}

__global__ void fb_fin(const float* __restrict__ acc, float* __restrict__ out)
{
    out[0] = acc[0] / (float)B_N;
    out[1] = acc[1] / (float)B_N;
    out[2] = acc[2] / ((float)(B_N - 1) * (float)B_N);
}

// ---------------------------------------------------------------------------
extern "C" void kernel_launch(void* const* d_in, const int* in_sizes, int n_in,
                              void* d_out, int out_size, void* d_ws, size_t ws_size,
                              hipStream_t stream)
{
    const float* A = (const float*)d_in[0];
    const float* P = (const float*)d_in[1];
    float* out = (float*)d_out;
    char* ws = (char*)d_ws;

    const size_t AF8_OFF  = 0;
    const size_t PF8_OFF  = AF8_OFF + (size_t)B_N * KPAD;
    const size_t REXP_OFF = PF8_OFF + (size_t)B_N * KPAD;
    const size_t RSUM_OFF = REXP_OFF + (size_t)B_N * sizeof(float);
    const size_t DIAG_OFF = RSUM_OFF + (size_t)B_N * sizeof(float);
    const size_t ACC_OFF  = DIAG_OFF + (size_t)B_N * sizeof(float);
    const size_t MAIN_REQ = ACC_OFF + 16;

    if (ws_size >= MAIN_REQ) {
        unsigned char* Af8 = (unsigned char*)(ws + AF8_OFF);
        unsigned char* Pf8 = (unsigned char*)(ws + PF8_OFF);
        float* rowexp = (float*)(ws + REXP_OFF);
        float* rowsum = (float*)(ws + RSUM_OFF);
        float* diag   = (float*)(ws + DIAG_OFF);
        float* acc    = (float*)(ws + ACC_OFF);

        normalize_kernel<<<dim3(B_N, 2), 192, 0, stream>>>(A, P, Af8, Pf8,
                                                           rowexp, rowsum, acc);
        gemm_fused_kernel<<<dim3(B_N / BM, COL_CHUNKS), 256, 0, stream>>>(
            Af8, Pf8, rowexp, rowsum, diag);
        finalize_partial<<<FIN_BLOCKS, 256, 0, stream>>>(rowexp, rowsum, diag, acc);
        finalize_write<<<1, 1, 0, stream>>>(acc, out);
    } else {
        // slow-but-correct fp32 fallback (needs ~96 KB ws)
        float* rna = (float*)ws;
        float* rnp = rna + B_N;
        float* acc = rnp + B_N;
        fb_norm<<<dim3(B_N, 2), 256, 0, stream>>>(A, P, rna, rnp, acc);
        fb_main<<<B_N, 256, 0, stream>>>(A, P, rna, rnp, acc);
        fb_fin<<<1, 1, 0, stream>>>(acc, out);
    }
}